// Round 16
// baseline (132.622 us; speedup 1.0000x reference)
//
#include <hip/hip_runtime.h>

typedef __attribute__((ext_vector_type(8))) short bf16x8;
typedef __attribute__((ext_vector_type(4))) short bf16x4;
typedef __attribute__((ext_vector_type(4))) float f32x4;

#define NB 128
#define LL 512
#define HH 128
#define HDIM 64
#define NROWS (NB * LL)  // 65536

__device__ __forceinline__ unsigned short f2b(float f) {
  unsigned int x = __float_as_uint(f);
  x = (x + 0x7fffu + ((x >> 16) & 1u)) >> 16;  // RNE
  return (unsigned short)x;
}

__device__ __forceinline__ bf16x8 load8_cvt(const float* p) {
  float4 a = *(const float4*)p;
  float4 b = *(const float4*)(p + 4);
  bf16x8 r;
  r[0] = (short)f2b(a.x); r[1] = (short)f2b(a.y);
  r[2] = (short)f2b(a.z); r[3] = (short)f2b(a.w);
  r[4] = (short)f2b(b.x); r[5] = (short)f2b(b.y);
  r[6] = (short)f2b(b.z); r[7] = (short)f2b(b.w);
  return r;
}

#if __has_builtin(__builtin_amdgcn_mfma_f32_16x16x16bf16_1k)
__device__ __forceinline__ f32x4 mfma16(bf16x4 a, bf16x4 b, f32x4 c) {
  return __builtin_amdgcn_mfma_f32_16x16x16bf16_1k(a, b, c, 0, 0, 0);
}
#else
__device__ __forceinline__ f32x4 mfma16(bf16x4 a, bf16x4 b, f32x4 c) {
  asm volatile("s_nop 1\n\t"
               "v_mfma_f32_16x16x16_bf16 %0, %1, %2, %0\n\t"
               "s_nop 7\n\t"
               "s_nop 7"
               : "+v"(c) : "v"(a), "v"(b));
  return c;
}
#endif

__device__ __forceinline__ f32x4 mfma32(bf16x8 a, bf16x8 b, f32x4 c) {
  return __builtin_amdgcn_mfma_f32_16x16x32_bf16(a, b, c, 0, 0, 0);
}

// ---------------------------------------------------------------------------
// Weight pre-convert: fp32 -> bf16, LINEAR layout Wb[3][128][128] (Q,K,V).
// ---------------------------------------------------------------------------
__global__ __launch_bounds__(256) void wcvt_kernel(
    const float* __restrict__ Qw, const float* __restrict__ Kw,
    const float* __restrict__ Vw, unsigned short* __restrict__ Wb) {
  const int i = blockIdx.x * 256 + threadIdx.x;  // 0..12287 float4s
  const float* src = (i < 4096) ? Qw : (i < 8192) ? Kw : Vw;
  const int off = (i & 4095) << 2;
  float4 v = *(const float4*)(src + off);
  ushort4 u;
  u.x = f2b(v.x); u.y = f2b(v.y); u.z = f2b(v.z); u.w = f2b(v.w);
  *(ushort4*)(Wb + ((size_t)i << 2)) = u;
}

// ---------------------------------------------------------------------------
// Fused kernel v3: one block per (b,h), 1024 thr = 16 waves, 128KB LDS.
// __launch_bounds__(1024, 4): request 4 waves/EU -> 128-VGPR budget (the
// plain (1024) variant targeted 8 waves/EU -> 64 VGPR -> 22MB scratch spill).
// Phase 1: wave w projects 32 rows -> K_lds + Vt. Phase 1.5: Qw over Kw.
// Phase 2: wave w handles paired 16-q chunks (31-w, w) = exactly 9 K-tiles.
// Kbias dropped (softmax-invariant); Vbias added in epilogue.
// ---------------------------------------------------------------------------
__global__ __launch_bounds__(1024, 4) void fused_kernel(
    const float* __restrict__ queries, const float* __restrict__ keys,
    const float* __restrict__ nbr, const float* __restrict__ nat,
    const float* __restrict__ pk, const float* __restrict__ pv,
    const unsigned short* __restrict__ Wb, const float* __restrict__ Qbias,
    const float* __restrict__ Vbias, unsigned short* __restrict__ Vt,
    float* __restrict__ out) {
  __shared__ unsigned short wlds[2 * 128 * 128];  // 64KB: [Kw->Qw | Vw->Qbounce]
  __shared__ unsigned short klds[512 * 64];       // 64KB: K' (swizzled rows)

  const int id = blockIdx.x;   // 0..255
  const int h = id >> 7;       // head
  const int b = id & 127;      // batch; h=0/1 of same b differ by 128 -> same XCD
  const int tid = threadIdx.x;
  const int lane = tid & 63;
  const int w = tid >> 6;      // wave 0..15
  const int g = lane >> 4;
  const int qi = lane & 15;
  const int rswz = (qi & 7) << 4;

  // ---- stage Kw,Vw (swizzle byte ^= ((row&7)<<4)) ----
#pragma unroll
  for (int i = 0; i < 4; ++i) {
    const int byte = (tid + i * 1024) * 16;  // [0, 65536)
    const int row = (byte >> 8) & 127;
    *(bf16x8*)((char*)wlds + (byte ^ ((row & 7) << 4))) =
        *(const bf16x8*)((const char*)Wb + 32768 + byte);
  }
  __syncthreads();

  // ================= Phase 1: K,V projections, 32 rows per wave ============
#pragma unroll
  for (int rg = 0; rg < 2; ++rg) {
    const int l = w * 32 + rg * 16 + qi;      // seq position 0..511
    const long roff = ((long)b * LL + l) * 128;

    bf16x8 xk[4];
#pragma unroll
    for (int kt = 0; kt < 4; ++kt)
      xk[kt] = load8_cvt(keys + roff + kt * 32 + g * 8);

    // K projection (Kw at LDS offset 0)
    f32x4 accK[4];
#pragma unroll
    for (int ct = 0; ct < 4; ++ct) {
      accK[ct] = f32x4{0.f, 0.f, 0.f, 0.f};
      const int rw = h * 64 + ct * 16 + qi;   // W row = out col
#pragma unroll
      for (int kt = 0; kt < 4; ++kt) {
        const int byte = rw * 256 + ((kt * 64 + g * 16) ^ rswz);
        bf16x8 wf = *(const bf16x8*)((const char*)wlds + byte);
        accK[ct] = mfma32(wf, xk[kt], accK[ct]);
      }
    }

    float4 tmp[4];
#pragma unroll
    for (int ct = 0; ct < 4; ++ct) {
      const int dl = ct * 16 + 4 * g;         // local col 0..63
      const int cg = h * 64 + dl;             // global col
      const float4 nb4 = *(const float4*)(nbr + roff + cg);
      const float4 na4 = *(const float4*)(nat + roff + cg);
      const float4 pk4 = *(const float4*)(pk + roff + cg);
      float4 t;
      t.x = nb4.x + na4.x; t.y = nb4.y + na4.y;
      t.z = nb4.z + na4.z; t.w = nb4.w + na4.w;
      tmp[ct] = t;
      ushort4 u;
      u.x = f2b(accK[ct][0] + t.x + pk4.x);
      u.y = f2b(accK[ct][1] + t.y + pk4.y);
      u.z = f2b(accK[ct][2] + t.z + pk4.z);
      u.w = f2b(accK[ct][3] + t.w + pk4.w);
      const int kb = l * 128 + dl * 2;
      *(ushort4*)((char*)klds + (kb ^ ((l & 7) << 4))) = u;
    }

    // V projection (Vw at LDS offset 32768)
    f32x4 accV[4];
#pragma unroll
    for (int ct = 0; ct < 4; ++ct) {
      accV[ct] = f32x4{0.f, 0.f, 0.f, 0.f};
      const int rw = h * 64 + ct * 16 + qi;
#pragma unroll
      for (int kt = 0; kt < 4; ++kt) {
        const int byte = 32768 + rw * 256 + ((kt * 64 + g * 16) ^ rswz);
        bf16x8 wf = *(const bf16x8*)((const char*)wlds + byte);
        accV[ct] = mfma32(wf, xk[kt], accV[ct]);
      }
    }
#pragma unroll
    for (int ct = 0; ct < 4; ++ct) {
      const int dl = ct * 16 + 4 * g;
      const int cg = h * 64 + dl;
      const float4 pv4 = *(const float4*)(pv + roff + cg);
      unsigned short* vp = Vt + (((long)h * NB + b) * HDIM + dl) * LL + l;
      vp[0 * LL] = f2b(accV[ct][0] + tmp[ct].x + pv4.x);
      vp[1 * LL] = f2b(accV[ct][1] + tmp[ct].y + pv4.y);
      vp[2 * LL] = f2b(accV[ct][2] + tmp[ct].z + pv4.z);
      vp[3 * LL] = f2b(accV[ct][3] + tmp[ct].w + pv4.w);
    }
  }

  __syncthreads();  // K_lds complete; Kw/Vw regions free

  // ---- stage Qw over the Kw region ----
#pragma unroll
  for (int i = 0; i < 2; ++i) {
    const int byte = (tid + i * 1024) * 16;  // [0, 32768)
    const int row = (byte >> 8) & 127;
    *(bf16x8*)((char*)wlds + (byte ^ ((row & 7) << 4))) =
        *(const bf16x8*)((const char*)Wb + byte);
  }
  __syncthreads();

  // ================= Phase 2: Q-proj + flash attention (16-q chunks) =======
  float vbe[4];
#pragma unroll
  for (int dt = 0; dt < 4; ++dt) vbe[dt] = Vbias[h * 64 + dt * 16 + qi];

  char* slot = (char*)wlds + 32768 + w * 2048;  // wave-private Q bounce
  const unsigned short* Vbase = Vt + ((long)h * NB + b) * HDIM * LL;

  for (int half = 0; half < 2; ++half) {
    const int j = half ? w : 31 - w;  // paired chunks: 9 tiles total, uniform
    const int qbase = j * 16;
    const int myq = qbase + qi;
    const int ntile = (j >> 2) + 1;

    // --- Q projection for 16 rows, bounced to B-fragment layout ---
    const long roff = ((long)b * LL + qbase + qi) * 128;
    bf16x8 xq[4];
#pragma unroll
    for (int kt = 0; kt < 4; ++kt)
      xq[kt] = load8_cvt(queries + roff + kt * 32 + g * 8);
    f32x4 aq[4];
#pragma unroll
    for (int ct = 0; ct < 4; ++ct) {
      aq[ct] = f32x4{0.f, 0.f, 0.f, 0.f};
      const int rw = h * 64 + ct * 16 + qi;
#pragma unroll
      for (int kt = 0; kt < 4; ++kt) {
        const int byte = rw * 256 + ((kt * 64 + g * 16) ^ rswz);
        bf16x8 wf = *(const bf16x8*)((const char*)wlds + byte);
        aq[ct] = mfma32(wf, xq[kt], aq[ct]);
      }
    }
#pragma unroll
    for (int ct = 0; ct < 4; ++ct) {
      const int dl = ct * 16 + 4 * g;
      const float4 bv = *(const float4*)(Qbias + h * 64 + dl);
      ushort4 u;
      u.x = f2b(aq[ct][0] + bv.x);
      u.y = f2b(aq[ct][1] + bv.y);
      u.z = f2b(aq[ct][2] + bv.z);
      u.w = f2b(aq[ct][3] + bv.w);
      const int bb = qi * 128 + dl * 2;
      *(ushort4*)(slot + (bb ^ ((qi & 7) << 4))) = u;
    }
    asm volatile("s_waitcnt lgkmcnt(0)" ::: "memory");
    __builtin_amdgcn_sched_barrier(0);
    const bf16x8 qf0 =
        *(const bf16x8*)(slot + ((qi * 128 + g * 16) ^ ((qi & 7) << 4)));
    const bf16x8 qf1 =
        *(const bf16x8*)(slot + ((qi * 128 + 64 + g * 16) ^ ((qi & 7) << 4)));

    // --- flash attention over K_lds / Vt ---
    f32x4 o[4];
#pragma unroll
    for (int dt = 0; dt < 4; ++dt) o[dt] = f32x4{0.f, 0.f, 0.f, 0.f};
    float m = -1e30f, lsum = 0.f;

    for (int it = 0; it < ntile; ++it) {
      const int k0 = it * 64;

      bf16x8 kf[4][2];
#pragma unroll
      for (int t = 0; t < 4; ++t) {
        const int l = k0 + t * 16 + qi;
        const int base = l * 128;
        const int sz = (l & 7) << 4;
        kf[t][0] = *(const bf16x8*)((char*)klds + ((base + g * 16) ^ sz));
        kf[t][1] = *(const bf16x8*)((char*)klds + ((base + 64 + g * 16) ^ sz));
      }

      bf16x4 vf[4][4];
#pragma unroll
      for (int dt = 0; dt < 4; ++dt)
#pragma unroll
        for (int t = 0; t < 4; ++t)
          vf[dt][t] = *(const bf16x4*)(Vbase + (dt * 16 + qi) * LL + k0 +
                                       t * 16 + 4 * g);

      f32x4 s[4];
#pragma unroll
      for (int t = 0; t < 4; ++t) {
        f32x4 acc = f32x4{0.f, 0.f, 0.f, 0.f};
        acc = mfma32(kf[t][0], qf0, acc);
        acc = mfma32(kf[t][1], qf1, acc);
        s[t] = acc;
      }

      float p[16];
      float pm = -1e30f;
#pragma unroll
      for (int t = 0; t < 4; ++t)
#pragma unroll
        for (int r = 0; r < 4; ++r) {
          float sv = s[t][r] * 0.125f;        // 1/sqrt(64)
          const int key = k0 + t * 16 + 4 * g + r;
          sv = (key > myq) ? -1e30f : sv;     // causal mask
          p[t * 4 + r] = sv;
          pm = fmaxf(pm, sv);
        }
      pm = fmaxf(pm, __shfl_xor(pm, 16));
      pm = fmaxf(pm, __shfl_xor(pm, 32));
      const float mnew = fmaxf(m, pm);
      const float alpha = exp2f((m - mnew) * 1.44269504f);
      float ps = 0.f;
#pragma unroll
      for (int i = 0; i < 16; ++i) {
        p[i] = exp2f((p[i] - mnew) * 1.44269504f);
        ps += p[i];
      }
      ps += __shfl_xor(ps, 16);
      ps += __shfl_xor(ps, 32);
      lsum = lsum * alpha + ps;
      m = mnew;

      bf16x4 pf[4];
#pragma unroll
      for (int t = 0; t < 4; ++t) {
        pf[t][0] = (short)f2b(p[t * 4 + 0]);
        pf[t][1] = (short)f2b(p[t * 4 + 1]);
        pf[t][2] = (short)f2b(p[t * 4 + 2]);
        pf[t][3] = (short)f2b(p[t * 4 + 3]);
      }

      float ar[4];
#pragma unroll
      for (int r = 0; r < 4; ++r) ar[r] = __shfl(alpha, 4 * g + r);

#pragma unroll
      for (int dt = 0; dt < 4; ++dt) {
        o[dt][0] *= ar[0];
        o[dt][1] *= ar[1];
        o[dt][2] *= ar[2];
        o[dt][3] *= ar[3];
#pragma unroll
        for (int t = 0; t < 4; ++t)
          o[dt] = mfma16(pf[t], vf[dt][t], o[dt]);
      }
    }

    // epilogue (+Vbias, exact since softmax weights sum to 1)
    float linv[4];
#pragma unroll
    for (int r = 0; r < 4; ++r) linv[r] = 1.0f / __shfl(lsum, 4 * g + r);
#pragma unroll
    for (int dt = 0; dt < 4; ++dt)
#pragma unroll
      for (int r = 0; r < 4; ++r) {
        const long row = (long)b * LL + qbase + 4 * g + r;
        out[row * HH + h * 64 + dt * 16 + qi] = o[dt][r] * linv[r] + vbe[dt];
      }
  }
}

extern "C" void kernel_launch(void* const* d_in, const int* in_sizes, int n_in,
                              void* d_out, int out_size, void* d_ws, size_t ws_size,
                              hipStream_t stream) {
  const float* queries = (const float*)d_in[0];
  const float* keys    = (const float*)d_in[1];
  const float* nbr     = (const float*)d_in[2];
  const float* nat     = (const float*)d_in[3];
  const float* pk      = (const float*)d_in[4];
  const float* pv      = (const float*)d_in[5];
  const float* Qw      = (const float*)d_in[6];
  const float* Qbias   = (const float*)d_in[7];
  const float* Kw      = (const float*)d_in[8];
  // const float* Kbias = (const float*)d_in[9];  // softmax-invariant: dropped
  const float* Vw      = (const float*)d_in[10];
  const float* Vbias   = (const float*)d_in[11];  // added in attn epilogue
  // d_in[12] = attn_mask: exact causal ~tril, computed analytically in-kernel.

  unsigned short* Vt = (unsigned short*)d_ws;            // [2][128][64][512] bf16
  unsigned short* Wb = Vt + (size_t)2 * NB * HDIM * LL;  // [3][128][128] bf16

  wcvt_kernel<<<48, 256, 0, stream>>>(Qw, Kw, Vw, Wb);

  fused_kernel<<<256, 1024, 0, stream>>>(queries, keys, nbr, nat, pk, pv, Wb,
                                         Qbias, Vbias, Vt, (float*)d_out);
}

// Round 17
// 84.404 us; speedup vs baseline: 1.5713x; 1.5713x over previous
//
#include <hip/hip_runtime.h>

typedef __attribute__((ext_vector_type(8))) short bf16x8;
typedef __attribute__((ext_vector_type(4))) short bf16x4;
typedef __attribute__((ext_vector_type(4))) float f32x4;

#define NB 128
#define LL 512
#define HH 128
#define HDIM 64
#define NROWS (NB * LL)  // 65536

__device__ __forceinline__ unsigned short f2b(float f) {
  unsigned int x = __float_as_uint(f);
  x = (x + 0x7fffu + ((x >> 16) & 1u)) >> 16;  // RNE
  return (unsigned short)x;
}

__device__ __forceinline__ bf16x8 load8_cvt(const float* p) {
  float4 a = *(const float4*)p;
  float4 b = *(const float4*)(p + 4);
  bf16x8 r;
  r[0] = (short)f2b(a.x); r[1] = (short)f2b(a.y);
  r[2] = (short)f2b(a.z); r[3] = (short)f2b(a.w);
  r[4] = (short)f2b(b.x); r[5] = (short)f2b(b.y);
  r[6] = (short)f2b(b.z); r[7] = (short)f2b(b.w);
  return r;
}

__device__ __forceinline__ bf16x8 cvt2(float4 a, float4 b) {
  bf16x8 r;
  r[0] = (short)f2b(a.x); r[1] = (short)f2b(a.y);
  r[2] = (short)f2b(a.z); r[3] = (short)f2b(a.w);
  r[4] = (short)f2b(b.x); r[5] = (short)f2b(b.y);
  r[6] = (short)f2b(b.z); r[7] = (short)f2b(b.w);
  return r;
}

#if __has_builtin(__builtin_amdgcn_mfma_f32_16x16x16bf16_1k)
__device__ __forceinline__ f32x4 mfma16(bf16x4 a, bf16x4 b, f32x4 c) {
  return __builtin_amdgcn_mfma_f32_16x16x16bf16_1k(a, b, c, 0, 0, 0);
}
#else
__device__ __forceinline__ f32x4 mfma16(bf16x4 a, bf16x4 b, f32x4 c) {
  asm volatile("s_nop 1\n\t"
               "v_mfma_f32_16x16x16_bf16 %0, %1, %2, %0\n\t"
               "s_nop 7\n\t"
               "s_nop 7"
               : "+v"(c) : "v"(a), "v"(b));
  return c;
}
#endif

__device__ __forceinline__ f32x4 mfma32(bf16x8 a, bf16x8 b, f32x4 c) {
  return __builtin_amdgcn_mfma_f32_16x16x32_bf16(a, b, c, 0, 0, 0);
}

// pinned 16B load: asm volatile cannot be sunk or reordered vs other asm
#define GLOAD(dst, base, OFF)                                        \
  asm volatile("global_load_dwordx4 %0, %1, off offset:" #OFF        \
               : "=v"(dst) : "v"(base))

// counted wait + sched_barrier(0) so dependent VALU isn't hoisted above it
#define VWAIT(N)                                                     \
  asm volatile("s_waitcnt vmcnt(" #N ")" ::: "memory");              \
  __builtin_amdgcn_sched_barrier(0)

// ---------------------------------------------------------------------------
// Weight pre-convert: fp32 -> bf16, LINEAR layout Wb[3][128][128] (Q,K,V).
// ---------------------------------------------------------------------------
__global__ __launch_bounds__(256) void wcvt_kernel(
    const float* __restrict__ Qw, const float* __restrict__ Kw,
    const float* __restrict__ Vw, unsigned short* __restrict__ Wb) {
  const int i = blockIdx.x * 256 + threadIdx.x;  // 0..12287 float4s
  const float* src = (i < 4096) ? Qw : (i < 8192) ? Kw : Vw;
  const int off = (i & 4095) << 2;
  float4 v = *(const float4*)(src + off);
  ushort4 u;
  u.x = f2b(v.x); u.y = f2b(v.y); u.z = f2b(v.z); u.w = f2b(v.w);
  *(ushort4*)(Wb + ((size_t)i << 2)) = u;
}

// ---------------------------------------------------------------------------
// Fused kernel v4 (R14 base + asm-pinned phase-1 load pipeline):
// one block per (b,h), 512 thr = 8 waves (2/SIMD -> 256-VGPR budget,
// declared via __launch_bounds__(512,2)), 128KB LDS.
// Phase 1: per wave 64 rows in 4 steps; keys(rg+1) + streams(rg) issued as
//   un-sinkable asm loads with counted vmcnt -> 24-40 outstanding loads/wave.
// Phase 1.5: Qw over Kw. Phase 2 (unchanged): paired 32-q chunks, 9 tiles.
// Kbias dropped (softmax-invariant); Vbias added in epilogue.
// ---------------------------------------------------------------------------
__global__ __launch_bounds__(512, 2) void fused_kernel(
    const float* __restrict__ queries, const float* __restrict__ keys,
    const float* __restrict__ nbr, const float* __restrict__ nat,
    const float* __restrict__ pk, const float* __restrict__ pv,
    const unsigned short* __restrict__ Wb, const float* __restrict__ Qbias,
    const float* __restrict__ Vbias, unsigned short* __restrict__ Vt,
    float* __restrict__ out) {
  __shared__ unsigned short wlds[2 * 128 * 128];  // 64KB: [Kw->Qw | Vw->Qbounce]
  __shared__ unsigned short klds[512 * 64];       // 64KB: K' (swizzled rows)

  const int id = blockIdx.x;   // 0..255
  const int h = id >> 7;       // head
  const int b = id & 127;      // batch; h=0/1 of same b differ by 128 -> same XCD
  const int tid = threadIdx.x;
  const int lane = tid & 63;
  const int w = tid >> 6;      // wave 0..7
  const int g = lane >> 4;
  const int qi = lane & 15;
  const int rswz = (qi & 7) << 4;

  // ---- stage Kw,Vw (swizzle byte ^= ((row&7)<<4)) ----
#pragma unroll
  for (int i = 0; i < 8; ++i) {
    const int byte = (tid + i * 512) * 16;  // [0, 65536)
    const int row = (byte >> 8) & 127;
    *(bf16x8*)((char*)wlds + (byte ^ ((row & 7) << 4))) =
        *(const bf16x8*)((const char*)Wb + 32768 + byte);
  }

  // ================= Phase 1: pinned-pipeline K,V projections ==============
  float4 ky0, ky1, ky2, ky3, ky4, ky5, ky6, ky7;
  float4 nb0, nb1, nb2, nb3, na0, na1, na2, na3;
  float4 pk0, pk1, pk2, pk3, pv0, pv1, pv2, pv3;
  bf16x8 xk0, xk1, xk2, xk3;

#define ISSUE_KEYS(RG)                                                       \
  {                                                                          \
    const float* kb =                                                        \
        keys + ((long)b * LL + w * 64 + (RG) * 16 + qi) * 128 + g * 8;       \
    GLOAD(ky0, kb, 0);   GLOAD(ky1, kb, 16);                                 \
    GLOAD(ky2, kb, 128); GLOAD(ky3, kb, 144);                                \
    GLOAD(ky4, kb, 256); GLOAD(ky5, kb, 272);                                \
    GLOAD(ky6, kb, 384); GLOAD(ky7, kb, 400);                                \
  }

#define ISSUE_STREAMS(RG)                                                    \
  {                                                                          \
    const long ro =                                                          \
        ((long)b * LL + w * 64 + (RG) * 16 + qi) * 128 + h * 64 + 4 * g;     \
    const float* p1 = nbr + ro; const float* p2 = nat + ro;                  \
    const float* p3 = pk + ro;  const float* p4 = pv + ro;                   \
    GLOAD(nb0, p1, 0); GLOAD(nb1, p1, 64); GLOAD(nb2, p1, 128); GLOAD(nb3, p1, 192); \
    GLOAD(na0, p2, 0); GLOAD(na1, p2, 64); GLOAD(na2, p2, 128); GLOAD(na3, p2, 192); \
    GLOAD(pk0, p3, 0); GLOAD(pk1, p3, 64); GLOAD(pk2, p3, 128); GLOAD(pk3, p3, 192); \
    GLOAD(pv0, p4, 0); GLOAD(pv1, p4, 64); GLOAD(pv2, p4, 128); GLOAD(pv3, p4, 192); \
  }

#define KEPI_CT(l, CT, NBv, NAv, PKv, TMPv)                                  \
  {                                                                          \
    TMPv.x = NBv.x + NAv.x; TMPv.y = NBv.y + NAv.y;                          \
    TMPv.z = NBv.z + NAv.z; TMPv.w = NBv.w + NAv.w;                          \
    ushort4 u;                                                               \
    u.x = f2b(accK[CT][0] + TMPv.x + PKv.x);                                 \
    u.y = f2b(accK[CT][1] + TMPv.y + PKv.y);                                 \
    u.z = f2b(accK[CT][2] + TMPv.z + PKv.z);                                 \
    u.w = f2b(accK[CT][3] + TMPv.w + PKv.w);                                 \
    const int kb2 = (l) * 128 + ((CT) * 16 + 4 * g) * 2;                     \
    *(ushort4*)((char*)klds + (kb2 ^ (((l) & 7) << 4))) = u;                 \
  }

#define VEPI_CT(l, CT, PVv, TMPv)                                            \
  {                                                                          \
    const int dl = (CT) * 16 + 4 * g;                                        \
    unsigned short* vp = Vt + (((long)h * NB + b) * HDIM + dl) * LL + (l);   \
    vp[0 * LL] = f2b(accV[CT][0] + TMPv.x + PVv.x);                          \
    vp[1 * LL] = f2b(accV[CT][1] + TMPv.y + PVv.y);                          \
    vp[2 * LL] = f2b(accV[CT][2] + TMPv.z + PVv.z);                          \
    vp[3 * LL] = f2b(accV[CT][3] + TMPv.w + PVv.w);                          \
  }

#define RG_STEP(RG, W0, W1, LAST)                                            \
  {                                                                          \
    const int l = w * 64 + (RG) * 16 + qi;                                   \
    VWAIT(W0);                                                               \
    xk0 = cvt2(ky0, ky1); xk1 = cvt2(ky2, ky3);                              \
    xk2 = cvt2(ky4, ky5); xk3 = cvt2(ky6, ky7);                              \
    ISSUE_STREAMS(RG);                                                       \
    if (!(LAST)) ISSUE_KEYS((RG) + 1);                                       \
    f32x4 accK[4];                                                           \
    _Pragma("unroll") for (int ct = 0; ct < 4; ++ct) {                       \
      accK[ct] = f32x4{0.f, 0.f, 0.f, 0.f};                                  \
      const int rw = h * 64 + ct * 16 + qi;                                  \
      {                                                                      \
        bf16x8 wf;                                                           \
        wf = *(const bf16x8*)((const char*)wlds + rw * 256 + ((0 * 64 + g * 16) ^ rswz)); \
        accK[ct] = mfma32(wf, xk0, accK[ct]);                                \
        wf = *(const bf16x8*)((const char*)wlds + rw * 256 + ((1 * 64 + g * 16) ^ rswz)); \
        accK[ct] = mfma32(wf, xk1, accK[ct]);                                \
        wf = *(const bf16x8*)((const char*)wlds + rw * 256 + ((2 * 64 + g * 16) ^ rswz)); \
        accK[ct] = mfma32(wf, xk2, accK[ct]);                                \
        wf = *(const bf16x8*)((const char*)wlds + rw * 256 + ((3 * 64 + g * 16) ^ rswz)); \
        accK[ct] = mfma32(wf, xk3, accK[ct]);                                \
      }                                                                      \
    }                                                                        \
    VWAIT(W1);                                                               \
    float4 tmp0, tmp1, tmp2, tmp3;                                           \
    KEPI_CT(l, 0, nb0, na0, pk0, tmp0);                                      \
    KEPI_CT(l, 1, nb1, na1, pk1, tmp1);                                      \
    KEPI_CT(l, 2, nb2, na2, pk2, tmp2);                                      \
    KEPI_CT(l, 3, nb3, na3, pk3, tmp3);                                      \
    f32x4 accV[4];                                                           \
    _Pragma("unroll") for (int ct = 0; ct < 4; ++ct) {                       \
      accV[ct] = f32x4{0.f, 0.f, 0.f, 0.f};                                  \
      const int rw = h * 64 + ct * 16 + qi;                                  \
      {                                                                      \
        bf16x8 wf;                                                           \
        wf = *(const bf16x8*)((const char*)wlds + 32768 + rw * 256 + ((0 * 64 + g * 16) ^ rswz)); \
        accV[ct] = mfma32(wf, xk0, accV[ct]);                                \
        wf = *(const bf16x8*)((const char*)wlds + 32768 + rw * 256 + ((1 * 64 + g * 16) ^ rswz)); \
        accV[ct] = mfma32(wf, xk1, accV[ct]);                                \
        wf = *(const bf16x8*)((const char*)wlds + 32768 + rw * 256 + ((2 * 64 + g * 16) ^ rswz)); \
        accV[ct] = mfma32(wf, xk2, accV[ct]);                                \
        wf = *(const bf16x8*)((const char*)wlds + 32768 + rw * 256 + ((3 * 64 + g * 16) ^ rswz)); \
        accV[ct] = mfma32(wf, xk3, accV[ct]);                                \
      }                                                                      \
    }                                                                        \
    VEPI_CT(l, 0, pv0, tmp0);                                                \
    VEPI_CT(l, 1, pv1, tmp1);                                                \
    VEPI_CT(l, 2, pv2, tmp2);                                                \
    VEPI_CT(l, 3, pv3, tmp3);                                                \
  }

  ISSUE_KEYS(0);     // prologue: keys(0) fly during LDS staging
  __syncthreads();   // weights staged

  RG_STEP(0, 0, 8, 0);
  RG_STEP(1, 16, 8, 0);
  RG_STEP(2, 16, 8, 0);
  RG_STEP(3, 16, 0, 1);

  __syncthreads();  // K_lds complete; Kw/Vw regions free

  // ---- stage Qw over the Kw region ----
#pragma unroll
  for (int i = 0; i < 4; ++i) {
    const int byte = (tid + i * 512) * 16;  // [0, 32768)
    const int row = (byte >> 8) & 127;
    *(bf16x8*)((char*)wlds + (byte ^ ((row & 7) << 4))) =
        *(const bf16x8*)((const char*)Wb + byte);
  }
  __syncthreads();

  // ================= Phase 2: Q-proj + flash attention (unchanged R14) =====
  float vbe[4];
#pragma unroll
  for (int dt = 0; dt < 4; ++dt) vbe[dt] = Vbias[h * 64 + dt * 16 + qi];

  char* slot = (char*)wlds + 32768 + w * 2048;  // wave-private Q bounce
  const unsigned short* Vbase = Vt + ((long)h * NB + b) * HDIM * LL;

  for (int half = 0; half < 2; ++half) {
    const int c = half ? w : 15 - w;  // paired chunks: 9 tiles total, uniform
    const int qbase = c * 32;
    const int ntile = (c >> 1) + 1;

    // --- Q projection for 32 rows, bounced to B-fragment layout ---
    bf16x8 qf[2][2];
#pragma unroll
    for (int q2 = 0; q2 < 2; ++q2) {
      const int l = qbase + q2 * 16 + qi;
      const long roff = ((long)b * LL + l) * 128;
      bf16x8 xq[4];
#pragma unroll
      for (int kt = 0; kt < 4; ++kt)
        xq[kt] = load8_cvt(queries + roff + kt * 32 + g * 8);
      f32x4 aq[4];
#pragma unroll
      for (int ct = 0; ct < 4; ++ct) {
        aq[ct] = f32x4{0.f, 0.f, 0.f, 0.f};
        const int rw = h * 64 + ct * 16 + qi;
#pragma unroll
        for (int kt = 0; kt < 4; ++kt) {
          const int byte = rw * 256 + ((kt * 64 + g * 16) ^ rswz);
          bf16x8 wf = *(const bf16x8*)((const char*)wlds + byte);
          aq[ct] = mfma32(wf, xq[kt], aq[ct]);
        }
      }
#pragma unroll
      for (int ct = 0; ct < 4; ++ct) {
        const int dl = ct * 16 + 4 * g;
        const float4 bv = *(const float4*)(Qbias + h * 64 + dl);
        ushort4 u;
        u.x = f2b(aq[ct][0] + bv.x);
        u.y = f2b(aq[ct][1] + bv.y);
        u.z = f2b(aq[ct][2] + bv.z);
        u.w = f2b(aq[ct][3] + bv.w);
        const int bb = qi * 128 + dl * 2;
        *(ushort4*)(slot + (bb ^ ((qi & 7) << 4))) = u;
      }
      asm volatile("s_waitcnt lgkmcnt(0)" ::: "memory");
      __builtin_amdgcn_sched_barrier(0);
      qf[q2][0] = *(const bf16x8*)(slot + ((qi * 128 + g * 16) ^ ((qi & 7) << 4)));
      qf[q2][1] = *(const bf16x8*)(slot + ((qi * 128 + 64 + g * 16) ^ ((qi & 7) << 4)));
    }

    // --- flash attention over K_lds / Vt ---
    f32x4 o[2][4];
#pragma unroll
    for (int q2 = 0; q2 < 2; ++q2)
#pragma unroll
      for (int dt = 0; dt < 4; ++dt) o[q2][dt] = f32x4{0.f, 0.f, 0.f, 0.f};
    float m[2] = {-1e30f, -1e30f};
    float lsum[2] = {0.f, 0.f};

    for (int it = 0; it < ntile; ++it) {
      const int k0 = it * 64;

      bf16x8 kf[4][2];
#pragma unroll
      for (int t = 0; t < 4; ++t) {
        const int l = k0 + t * 16 + qi;
        const int base = l * 128;
        const int sz = (l & 7) << 4;
        kf[t][0] = *(const bf16x8*)((char*)klds + ((base + g * 16) ^ sz));
        kf[t][1] = *(const bf16x8*)((char*)klds + ((base + 64 + g * 16) ^ sz));
      }

      bf16x4 vf[4][4];
#pragma unroll
      for (int dt = 0; dt < 4; ++dt)
#pragma unroll
        for (int t = 0; t < 4; ++t)
          vf[dt][t] = *(const bf16x4*)(Vbase + (dt * 16 + qi) * LL + k0 +
                                       t * 16 + 4 * g);

      f32x4 s[2][4];
#pragma unroll
      for (int q2 = 0; q2 < 2; ++q2)
#pragma unroll
        for (int t = 0; t < 4; ++t) {
          f32x4 acc = f32x4{0.f, 0.f, 0.f, 0.f};
          acc = mfma32(kf[t][0], qf[q2][0], acc);
          acc = mfma32(kf[t][1], qf[q2][1], acc);
          s[q2][t] = acc;
        }

      float alpha[2];
      bf16x4 pf[2][4];
#pragma unroll
      for (int q2 = 0; q2 < 2; ++q2) {
        const int myq = qbase + q2 * 16 + qi;
        float p[16];
        float pm = -1e30f;
#pragma unroll
        for (int t = 0; t < 4; ++t)
#pragma unroll
          for (int r = 0; r < 4; ++r) {
            float sv = s[q2][t][r] * 0.125f;    // 1/sqrt(64)
            const int key = k0 + t * 16 + 4 * g + r;
            sv = (key > myq) ? -1e30f : sv;     // causal mask
            p[t * 4 + r] = sv;
            pm = fmaxf(pm, sv);
          }
        pm = fmaxf(pm, __shfl_xor(pm, 16));
        pm = fmaxf(pm, __shfl_xor(pm, 32));
        const float mnew = fmaxf(m[q2], pm);
        alpha[q2] = exp2f((m[q2] - mnew) * 1.44269504f);
        float ps = 0.f;
#pragma unroll
        for (int i = 0; i < 16; ++i) {
          p[i] = exp2f((p[i] - mnew) * 1.44269504f);
          ps += p[i];
        }
        ps += __shfl_xor(ps, 16);
        ps += __shfl_xor(ps, 32);
        lsum[q2] = lsum[q2] * alpha[q2] + ps;
        m[q2] = mnew;
#pragma unroll
        for (int t = 0; t < 4; ++t) {
          pf[q2][t][0] = (short)f2b(p[t * 4 + 0]);
          pf[q2][t][1] = (short)f2b(p[t * 4 + 1]);
          pf[q2][t][2] = (short)f2b(p[t * 4 + 2]);
          pf[q2][t][3] = (short)f2b(p[t * 4 + 3]);
        }
      }

      float ar[2][4];
#pragma unroll
      for (int q2 = 0; q2 < 2; ++q2)
#pragma unroll
        for (int r = 0; r < 4; ++r) ar[q2][r] = __shfl(alpha[q2], 4 * g + r);

#pragma unroll
      for (int dt = 0; dt < 4; ++dt) {
#pragma unroll
        for (int q2 = 0; q2 < 2; ++q2) {
          o[q2][dt][0] *= ar[q2][0];
          o[q2][dt][1] *= ar[q2][1];
          o[q2][dt][2] *= ar[q2][2];
          o[q2][dt][3] *= ar[q2][3];
        }
#pragma unroll
        for (int t = 0; t < 4; ++t) {
          o[0][dt] = mfma16(pf[0][t], vf[dt][t], o[0][dt]);
          o[1][dt] = mfma16(pf[1][t], vf[dt][t], o[1][dt]);
        }
      }
    }

    // epilogue (+Vbias, exact since softmax weights sum to 1)
#pragma unroll
    for (int q2 = 0; q2 < 2; ++q2) {
      float linv[4];
#pragma unroll
      for (int r = 0; r < 4; ++r) linv[r] = 1.0f / __shfl(lsum[q2], 4 * g + r);
#pragma unroll
      for (int dt = 0; dt < 4; ++dt)
#pragma unroll
        for (int r = 0; r < 4; ++r) {
          const long row = (long)b * LL + qbase + q2 * 16 + 4 * g + r;
          out[row * HH + h * 64 + dt * 16 + qi] =
              o[q2][dt][r] * linv[r] + vbe[dt];
        }
    }
  }
}

extern "C" void kernel_launch(void* const* d_in, const int* in_sizes, int n_in,
                              void* d_out, int out_size, void* d_ws, size_t ws_size,
                              hipStream_t stream) {
  const float* queries = (const float*)d_in[0];
  const float* keys    = (const float*)d_in[1];
  const float* nbr     = (const float*)d_in[2];
  const float* nat     = (const float*)d_in[3];
  const float* pk      = (const float*)d_in[4];
  const float* pv      = (const float*)d_in[5];
  const float* Qw      = (const float*)d_in[6];
  const float* Qbias   = (const float*)d_in[7];
  const float* Kw      = (const float*)d_in[8];
  // const float* Kbias = (const float*)d_in[9];  // softmax-invariant: dropped
  const float* Vw      = (const float*)d_in[10];
  const float* Vbias   = (const float*)d_in[11];  // added in attn epilogue
  // d_in[12] = attn_mask: exact causal ~tril, computed analytically in-kernel.

  unsigned short* Vt = (unsigned short*)d_ws;            // [2][128][64][512] bf16
  unsigned short* Wb = Vt + (size_t)2 * NB * HDIM * LL;  // [3][128][128] bf16

  wcvt_kernel<<<48, 256, 0, stream>>>(Qw, Kw, Vw, Wb);

  fused_kernel<<<256, 512, 0, stream>>>(queries, keys, nbr, nat, pk, pv, Wb,
                                        Qbias, Vbias, Vt, (float*)d_out);
}